// Round 2
// baseline (552.367 us; speedup 1.0000x reference)
//
#include <hip/hip_runtime.h>

// Problem constants (fixed by setup_inputs): b=4, n=16384, c=256, t=64,
// heads=8, d=32, group=128, ngroups=128, pad_n=0.
#define BB   4
#define NN   16384
#define CC   256
#define TT   64
#define HH   8
#define DD   32
#define GSZ  128
#define NGR  128

typedef __attribute__((ext_vector_type(8))) short s16x8;
typedef __attribute__((ext_vector_type(4))) float f32x4;

__device__ __forceinline__ unsigned short f2bf(float f) {
  unsigned int u = __float_as_uint(f);
  u += 0x7FFFu + ((u >> 16) & 1u);   // RNE to bf16
  return (unsigned short)(u >> 16);
}

// ---------------------------------------------------------------------------
// K1: per-token argmax over 64 categories (first-max = jnp.argmax) + histogram
// ---------------------------------------------------------------------------
__global__ __launch_bounds__(256) void cat_hist_kernel(
    const float* __restrict__ sim, int* __restrict__ cat, int* __restrict__ hist)
{
  const int idx = blockIdx.x * 256 + threadIdx.x;      // token over b*n
  const float4* row = (const float4*)(sim + (size_t)idx * TT);
  float best = -3.4e38f; int bi = 0;
  #pragma unroll
  for (int j = 0; j < TT / 4; j++) {
    float4 v = row[j];
    if (v.x > best) { best = v.x; bi = j * 4 + 0; }
    if (v.y > best) { best = v.y; bi = j * 4 + 1; }
    if (v.z > best) { best = v.z; bi = j * 4 + 2; }
    if (v.w > best) { best = v.w; bi = j * 4 + 3; }
  }
  cat[idx] = bi;
  atomicAdd(&hist[((idx >> 14) << 6) + bi], 1);        // b = idx/N (N=2^14)
}

// ---------------------------------------------------------------------------
// K2: exclusive prefix over categories per batch
// ---------------------------------------------------------------------------
__global__ void prefix_kernel(const int* __restrict__ hist, int* __restrict__ catStart)
{
  int b = threadIdx.x;
  if (b < BB) {
    int acc = 0;
    for (int c = 0; c < TT; c++) { catStart[b * TT + c] = acc; acc += hist[b * TT + c]; }
  }
}

// ---------------------------------------------------------------------------
// K3: stable counting-sort positions. Block (b,c): 256 threads x 64-token
// chunks; block-scan gives stable ranks; writes srcOf[b][dst] = src.
// ---------------------------------------------------------------------------
__global__ __launch_bounds__(256) void sort_positions_kernel(
    const int* __restrict__ cat, const int* __restrict__ catStart, int* __restrict__ srcOf)
{
  const int b = blockIdx.x >> 6;
  const int c = blockIdx.x & 63;
  const int* catb = cat + (size_t)b * NN;
  const int tid = threadIdx.x;
  const int beg = tid * (NN / 256);                    // 64 tokens per thread
  int cnt = 0;
  for (int i = 0; i < NN / 256; i++) cnt += (catb[beg + i] == c);
  __shared__ int sc[256];
  sc[tid] = cnt; __syncthreads();
  for (int off = 1; off < 256; off <<= 1) {
    int v = (tid >= off) ? sc[tid - off] : 0;
    __syncthreads();
    sc[tid] += v;
    __syncthreads();
  }
  int pos = catStart[(b << 6) + c] + sc[tid] - cnt;    // exclusive rank
  int* dst = srcOf + (size_t)b * NN;
  for (int i = 0; i < NN / 256; i++) {
    int t = beg + i;
    if (catb[t] == c) dst[pos++] = t;
  }
}

// ---------------------------------------------------------------------------
// K4: attention per (b, group, head). fp32 vector math.
// Thread owns 4 rows x 16 cols; Qt/Kt/Vt transposed in LDS; P kept in regs;
// PV partials reduced across the 8 col-group lanes via shuffles.
// Gathers qkv rows via srcOf, scatters y (bf16) back via the same index.
// ---------------------------------------------------------------------------
__global__ __launch_bounds__(256) void attn_kernel(
    const float* __restrict__ qkv, const int* __restrict__ srcOf,
    const float* __restrict__ lsp, unsigned short* __restrict__ xb)
{
  __shared__ float Qt[DD][GSZ];
  __shared__ float Kt[DD][GSZ];
  __shared__ float Vt[DD][GSZ];
  __shared__ int srcL[GSZ];

  const int bid = blockIdx.x;
  const int h = bid & 7;
  const int g = (bid >> 3) & (NGR - 1);
  const int b = bid >> 10;
  const int tid = threadIdx.x;

  // scale = exp(min(logit_scale, log(100)))
  const float scale = __expf(fminf(lsp[0], 4.6051702f));

  if (tid < GSZ) srcL[tid] = srcOf[b * NN + g * GSZ + tid];
  __syncthreads();

  { // stage q (pre-scaled), k, v — transposed into LDS
    const int tok = tid >> 1;
    const int fh = (tid & 1) * 16;
    const float* bp = qkv + ((size_t)(b * NN + srcL[tok])) * (3 * CC) + h * DD + fh;
    #pragma unroll
    for (int u = 0; u < 4; u++) {
      float4 q4 = *(const float4*)(bp + u * 4);
      float4 k4 = *(const float4*)(bp + CC + u * 4);
      float4 v4 = *(const float4*)(bp + 2 * CC + u * 4);
      int d = fh + u * 4;
      Qt[d + 0][tok] = q4.x * scale; Qt[d + 1][tok] = q4.y * scale;
      Qt[d + 2][tok] = q4.z * scale; Qt[d + 3][tok] = q4.w * scale;
      Kt[d + 0][tok] = k4.x; Kt[d + 1][tok] = k4.y;
      Kt[d + 2][tok] = k4.z; Kt[d + 3][tok] = k4.w;
      Vt[d + 0][tok] = v4.x; Vt[d + 1][tok] = v4.y;
      Vt[d + 2][tok] = v4.z; Vt[d + 3][tok] = v4.w;
    }
  }
  __syncthreads();

  const int rg = tid >> 3, cg = tid & 7;
  const int r0 = rg * 4, c0 = cg * 16;

  float s[4][16];
  #pragma unroll
  for (int r = 0; r < 4; r++)
    #pragma unroll
    for (int t = 0; t < 16; t++) s[r][t] = 0.f;

  // QK^T: outer product over k-dim
  #pragma unroll 4
  for (int i = 0; i < DD; i++) {
    float4 q4 = *(const float4*)&Qt[i][r0];
    float qr[4] = {q4.x, q4.y, q4.z, q4.w};
    float4 ka = *(const float4*)&Kt[i][c0];
    float4 kb2 = *(const float4*)&Kt[i][c0 + 4];
    float4 kc2 = *(const float4*)&Kt[i][c0 + 8];
    float4 kd2 = *(const float4*)&Kt[i][c0 + 12];
    float kk[16] = {ka.x, ka.y, ka.z, ka.w, kb2.x, kb2.y, kb2.z, kb2.w,
                    kc2.x, kc2.y, kc2.z, kc2.w, kd2.x, kd2.y, kd2.z, kd2.w};
    #pragma unroll
    for (int r = 0; r < 4; r++)
      #pragma unroll
      for (int t = 0; t < 16; t++)
        s[r][t] = fmaf(qr[r], kk[t], s[r][t]);
  }

  // row softmax (rows split across 8 cg lanes; xor-reduce over cg bits)
  float m[4], l[4], inv[4];
  #pragma unroll
  for (int r = 0; r < 4; r++) {
    float mm = -3.4e38f;
    #pragma unroll
    for (int t = 0; t < 16; t++) mm = fmaxf(mm, s[r][t]);
    mm = fmaxf(mm, __shfl_xor(mm, 1));
    mm = fmaxf(mm, __shfl_xor(mm, 2));
    mm = fmaxf(mm, __shfl_xor(mm, 4));
    m[r] = mm;
  }
  #pragma unroll
  for (int r = 0; r < 4; r++) {
    float acc = 0.f;
    #pragma unroll
    for (int t = 0; t < 16; t++) {
      float e = __expf(s[r][t] - m[r]);
      s[r][t] = e; acc += e;
    }
    acc += __shfl_xor(acc, 1);
    acc += __shfl_xor(acc, 2);
    acc += __shfl_xor(acc, 4);
    l[r] = acc;
    inv[r] = 1.0f / acc;
  }

  // PV in 4 passes of 8 dims; reduce partials over cg; scatter-store bf16
  #pragma unroll 1
  for (int ps = 0; ps < 4; ps++) {
    const int d0 = ps * 8;
    float y[4][8];
    #pragma unroll
    for (int r = 0; r < 4; r++)
      #pragma unroll
      for (int j = 0; j < 8; j++) y[r][j] = 0.f;

    #pragma unroll
    for (int j = 0; j < 8; j++) {
      float4 va = *(const float4*)&Vt[d0 + j][c0];
      float4 vb3 = *(const float4*)&Vt[d0 + j][c0 + 4];
      float4 vc3 = *(const float4*)&Vt[d0 + j][c0 + 8];
      float4 vd3 = *(const float4*)&Vt[d0 + j][c0 + 12];
      float vv[16] = {va.x, va.y, va.z, va.w, vb3.x, vb3.y, vb3.z, vb3.w,
                      vc3.x, vc3.y, vc3.z, vc3.w, vd3.x, vd3.y, vd3.z, vd3.w};
      #pragma unroll
      for (int r = 0; r < 4; r++) {
        float acc = y[r][j];
        #pragma unroll
        for (int t = 0; t < 16; t++) acc = fmaf(s[r][t], vv[t], acc);
        y[r][j] = acc;
      }
    }
    #pragma unroll
    for (int r = 0; r < 4; r++)
      #pragma unroll
      for (int j = 0; j < 8; j++) {
        y[r][j] += __shfl_xor(y[r][j], 1);
        y[r][j] += __shfl_xor(y[r][j], 2);
        y[r][j] += __shfl_xor(y[r][j], 4);
      }
    if (cg == 0) {
      #pragma unroll
      for (int r = 0; r < 4; r++) {
        const int row = r0 + r;
        const int src = srcL[row];
        s16x8 pk;
        #pragma unroll
        for (int j = 0; j < 8; j++) pk[j] = (short)f2bf(y[r][j] * inv[r]);
        *(s16x8*)&xb[((size_t)(b * NN + src)) * CC + h * DD + d0] = pk;
      }
    }
  }
}

// ---------------------------------------------------------------------------
// K5: projection out = x_bf16 @ W^T + bias via mfma_f32_16x16x32_bf16.
// Wave owns 16 m-rows x 64 n-cols; W-fragments cached in VGPRs; grid-stride
// over 4096 m-tiles. A and B frags: lane&15 = row/col, k = (lane>>4)*8 + j.
// ---------------------------------------------------------------------------
__global__ __launch_bounds__(256) void proj_kernel(
    const unsigned short* __restrict__ xb, const float* __restrict__ W,
    const float* __restrict__ bias, float* __restrict__ out)
{
  const int tid = threadIdx.x;
  const int wave = tid >> 6;
  const int lane = tid & 63;
  const int n0 = wave * 64;
  const int lr = lane & 15;       // row (A) / col (B) within tile
  const int kb = lane >> 4;       // k-block 0..3

  // cache W fragments (bf16) for this wave's 4 n-tiles x 8 k-steps
  s16x8 wf[4][8];
  #pragma unroll
  for (int nt = 0; nt < 4; nt++)
    #pragma unroll
    for (int ks = 0; ks < 8; ks++) {
      const float* wp = W + (size_t)(n0 + nt * 16 + lr) * CC + ks * 32 + kb * 8;
      float4 w0 = *(const float4*)wp;
      float4 w1 = *(const float4*)(wp + 4);
      s16x8 wv;
      wv[0] = (short)f2bf(w0.x); wv[1] = (short)f2bf(w0.y);
      wv[2] = (short)f2bf(w0.z); wv[3] = (short)f2bf(w0.w);
      wv[4] = (short)f2bf(w1.x); wv[5] = (short)f2bf(w1.y);
      wv[6] = (short)f2bf(w1.z); wv[7] = (short)f2bf(w1.w);
      wf[nt][ks] = wv;
    }
  float bs[4];
  #pragma unroll
  for (int nt = 0; nt < 4; nt++) bs[nt] = bias[n0 + nt * 16 + lr];

  const int MT = (BB * NN) / 16;  // 4096 m-tiles
  for (int mt = blockIdx.x; mt < MT; mt += gridDim.x) {
    const int m0 = mt * 16;
    const unsigned short* xrow = xb + (size_t)(m0 + lr) * CC + kb * 8;
    s16x8 a[8];
    #pragma unroll
    for (int ks = 0; ks < 8; ks++) a[ks] = *(const s16x8*)(xrow + ks * 32);
    #pragma unroll
    for (int nt = 0; nt < 4; nt++) {
      f32x4 acc = {0.f, 0.f, 0.f, 0.f};
      #pragma unroll
      for (int ks = 0; ks < 8; ks++)
        acc = __builtin_amdgcn_mfma_f32_16x16x32_bf16(a[ks], wf[nt][ks], acc, 0, 0, 0);
      const int ccol = n0 + nt * 16 + lr;
      #pragma unroll
      for (int q = 0; q < 4; q++) {
        const int row = m0 + kb * 4 + q;   // D: row=(lane>>4)*4+reg, col=lane&15
        out[(size_t)row * CC + ccol] = acc[q] + bs[nt];
      }
    }
  }
}

// ---------------------------------------------------------------------------
extern "C" void kernel_launch(void* const* d_in, const int* in_sizes, int n_in,
                              void* d_out, int out_size, void* d_ws, size_t ws_size,
                              hipStream_t stream)
{
  (void)in_sizes; (void)n_in; (void)out_size; (void)ws_size;
  const float* qkv  = (const float*)d_in[0];
  const float* sim  = (const float*)d_in[1];
  const float* W    = (const float*)d_in[2];
  const float* bias = (const float*)d_in[3];
  const float* lsp  = (const float*)d_in[4];
  float* out = (float*)d_out;

  // workspace layout (~34.1 MB)
  char* ws = (char*)d_ws;
  unsigned short* xb = (unsigned short*)ws;                 // [B*N][C] bf16, 32 MB
  size_t off = (size_t)BB * NN * CC * sizeof(unsigned short);
  int* srcOf = (int*)(ws + off); off += (size_t)BB * NN * sizeof(int);
  int* cat   = (int*)(ws + off); off += (size_t)BB * NN * sizeof(int);
  int* hist  = (int*)(ws + off); off += (size_t)BB * TT * sizeof(int);
  int* catStart = (int*)(ws + off);

  hipMemsetAsync(hist, 0, BB * TT * sizeof(int), stream);
  cat_hist_kernel<<<(BB * NN) / 256, 256, 0, stream>>>(sim, cat, hist);
  prefix_kernel<<<1, 64, 0, stream>>>(hist, catStart);
  sort_positions_kernel<<<BB * TT, 256, 0, stream>>>(cat, catStart, srcOf);
  attn_kernel<<<BB * NGR * HH, 256, 0, stream>>>(qkv, srcOf, lsp, xb);
  proj_kernel<<<512, 256, 0, stream>>>(xb, W, bias, out);
}

// Round 5
// 442.274 us; speedup vs baseline: 1.2489x; 1.2489x over previous
//
#include <hip/hip_runtime.h>

// Problem constants (fixed by setup_inputs): b=4, n=16384, c=256, t=64,
// heads=8, d=32, group=128, ngroups=128, pad_n=0.
#define BB   4
#define NN   16384
#define CC   256
#define TT   64
#define HH   8
#define DD   32
#define GSZ  128
#define NGR  128

typedef __attribute__((ext_vector_type(8))) short s16x8;
typedef __attribute__((ext_vector_type(4))) float f32x4;
typedef __attribute__((ext_vector_type(16))) float f32x16;
typedef __attribute__((ext_vector_type(4))) unsigned int u32x4;

union FragU { u32x4 u; s16x8 s; };

__device__ __forceinline__ unsigned short f2bf(float f) {
  unsigned int u = __float_as_uint(f);
  u += 0x7FFFu + ((u >> 16) & 1u);   // RNE to bf16
  return (unsigned short)(u >> 16);
}

// packed bf16 pair: lo = bf16(a), hi = bf16(b)  (v_cvt_pk_bf16_f32, RNE)
__device__ __forceinline__ unsigned int cvtpk_bf16(float a, float b) {
  unsigned int r;
  asm("v_cvt_pk_bf16_f32 %0, %1, %2" : "=v"(r) : "v"(a), "v"(b));
  return r;
}

// split two floats into packed bf16 hi-pair and lo-pair (hi + lo ≈ f exactly)
__device__ __forceinline__ void split2(float a, float b,
                                       unsigned int& wh, unsigned int& wl) {
  wh = cvtpk_bf16(a, b);
  float ra = __uint_as_float(wh << 16);
  float rb = __uint_as_float(wh & 0xffff0000u);
  wl = cvtpk_bf16(a - ra, b - rb);
}

// ---------------------------------------------------------------------------
// K1: per-token argmax over 64 categories (first-max = jnp.argmax) + histogram
// ---------------------------------------------------------------------------
__global__ __launch_bounds__(256) void cat_hist_kernel(
    const float* __restrict__ sim, int* __restrict__ cat, int* __restrict__ hist)
{
  const int idx = blockIdx.x * 256 + threadIdx.x;      // token over b*n
  const float4* row = (const float4*)(sim + (size_t)idx * TT);
  float best = -3.4e38f; int bi = 0;
  #pragma unroll
  for (int j = 0; j < TT / 4; j++) {
    float4 v = row[j];
    if (v.x > best) { best = v.x; bi = j * 4 + 0; }
    if (v.y > best) { best = v.y; bi = j * 4 + 1; }
    if (v.z > best) { best = v.z; bi = j * 4 + 2; }
    if (v.w > best) { best = v.w; bi = j * 4 + 3; }
  }
  cat[idx] = bi;
  atomicAdd(&hist[((idx >> 14) << 6) + bi], 1);        // b = idx/N (N=2^14)
}

// ---------------------------------------------------------------------------
// K2: exclusive prefix over categories per batch
// ---------------------------------------------------------------------------
__global__ void prefix_kernel(const int* __restrict__ hist, int* __restrict__ catStart)
{
  int b = threadIdx.x;
  if (b < BB) {
    int acc = 0;
    for (int c = 0; c < TT; c++) { catStart[b * TT + c] = acc; acc += hist[b * TT + c]; }
  }
}

// ---------------------------------------------------------------------------
// K3: stable counting-sort positions. Block (b,c): 256 threads x 64-token
// chunks; block-scan gives stable ranks; writes srcOf[b][dst] = src.
// ---------------------------------------------------------------------------
__global__ __launch_bounds__(256) void sort_positions_kernel(
    const int* __restrict__ cat, const int* __restrict__ catStart, int* __restrict__ srcOf)
{
  const int b = blockIdx.x >> 6;
  const int c = blockIdx.x & 63;
  const int* catb = cat + (size_t)b * NN;
  const int tid = threadIdx.x;
  const int beg = tid * (NN / 256);                    // 64 tokens per thread
  int cnt = 0;
  for (int i = 0; i < NN / 256; i++) cnt += (catb[beg + i] == c);
  __shared__ int sc[256];
  sc[tid] = cnt; __syncthreads();
  for (int off = 1; off < 256; off <<= 1) {
    int v = (tid >= off) ? sc[tid - off] : 0;
    __syncthreads();
    sc[tid] += v;
    __syncthreads();
  }
  int pos = catStart[(b << 6) + c] + sc[tid] - cnt;    // exclusive rank
  int* dst = srcOf + (size_t)b * NN;
  for (int i = 0; i < NN / 256; i++) {
    int t = beg + i;
    if (catb[t] == c) dst[pos++] = t;
  }
}

// ---------------------------------------------------------------------------
// K4: MFMA attention per (b, group, head). 4 waves; wave w owns q-rows
// 32w..32w+31. Swapped QK^T: S^T = mfma(A=K, B=Q^T) (32x32x16, hi/lo bf16
// split x3 terms for fp32-accurate logits) -> per-lane P row (q = lane&31).
// Softmax in-lane + shfl_xor(32). PV as y^T = mfma(A=V^T from LDS, B=P^T
// in-reg via cvt_pk + 2 shfl per kstep). Q/K fragments gathered directly
// from global; only V staged in LDS (transposed, XOR-swizzled).
// ---------------------------------------------------------------------------
__global__ __launch_bounds__(256) void attn_kernel(
    const float* __restrict__ qkv, const int* __restrict__ srcOf,
    const float* __restrict__ lsp, unsigned short* __restrict__ xb)
{
  __shared__ int srcLs[GSZ];
  __shared__ unsigned short VtL[DD * GSZ];   // [dim][kcol], 16B-chunk swizzled

  const int bid = blockIdx.x;
  const int hH = bid & 7;                    // head
  const int g = (bid >> 3) & (NGR - 1);
  const int b = bid >> 10;
  const int tid = threadIdx.x;
  const int lane = tid & 63;
  const int wid = tid >> 6;
  const int ql = lane & 31;                  // q (or token) index within tile
  const int hf = lane >> 5;                  // lane half

  const float scale = __expf(fminf(lsp[0], 4.6051702f));
  const float* qkvB = qkv + (size_t)b * NN * (3 * CC);

  if (tid < GSZ) srcLs[tid] = srcOf[b * NN + g * GSZ + tid];
  __syncthreads();

  // ---- stage V transposed into LDS (bf16, swizzled), via token-pairs ----
  {
    const int tp = tid & 63;                 // token pair id
    const int o = tid >> 6;                  // dim octet 0..3
    const int t0 = srcLs[2 * tp], t1 = srcLs[2 * tp + 1];
    const float* v0p = qkvB + (size_t)t0 * (3 * CC) + 2 * CC + hH * DD + 8 * o;
    const float* v1p = qkvB + (size_t)t1 * (3 * CC) + 2 * CC + hH * DD + 8 * o;
    float4 a0 = *(const float4*)v0p, a1 = *(const float4*)(v0p + 4);
    float4 b0 = *(const float4*)v1p, b1 = *(const float4*)(v1p + 4);
    float va[8] = {a0.x, a0.y, a0.z, a0.w, a1.x, a1.y, a1.z, a1.w};
    float vb[8] = {b0.x, b0.y, b0.z, b0.w, b1.x, b1.y, b1.z, b1.w};
    #pragma unroll
    for (int u = 0; u < 8; u++) {
      const int dim = 8 * o + u;
      unsigned int val = cvtpk_bf16(va[u], vb[u]);     // {tok 2tp, tok 2tp+1}
      const int byte = dim * 256 + ((((tp >> 2) ^ (dim & 15))) << 4) + ((4 * tp) & 15);
      *(unsigned int*)((char*)VtL + byte) = val;
    }
  }

  // ---- gather Q fragments (own q-row), pre-scaled, hi/lo split ----
  const int tokQ = srcLs[32 * wid + ql];
  FragU qh[2], qlo[2];
  {
    const float* qp = qkvB + (size_t)tokQ * (3 * CC) + hH * DD;
    #pragma unroll
    for (int ks = 0; ks < 2; ks++) {
      const float* p8 = qp + 16 * ks + 8 * hf;
      float4 f0 = *(const float4*)p8, f1 = *(const float4*)(p8 + 4);
      float f[8] = {f0.x * scale, f0.y * scale, f0.z * scale, f0.w * scale,
                    f1.x * scale, f1.y * scale, f1.z * scale, f1.w * scale};
      #pragma unroll
      for (int c = 0; c < 4; c++) {
        unsigned int wh, wl;
        split2(f[2 * c], f[2 * c + 1], wh, wl);
        qh[ks].u[c] = wh; qlo[ks].u[c] = wl;
      }
    }
  }

  __syncthreads();   // VtL ready (QK^T below doesn't need it, PV does)

  // ---- QK^T: S^T[kcol][q], 4 M-tiles over kcol ----
  f32x16 accS[4];
  #pragma unroll
  for (int mt = 0; mt < 4; mt++) {
    #pragma unroll
    for (int r = 0; r < 16; r++) accS[mt][r] = 0.f;
    const int tokK = srcLs[32 * mt + ql];
    const float* kp = qkvB + (size_t)tokK * (3 * CC) + CC + hH * DD;
    #pragma unroll
    for (int ks = 0; ks < 2; ks++) {
      const float* p8 = kp + 16 * ks + 8 * hf;
      float4 f0 = *(const float4*)p8, f1 = *(const float4*)(p8 + 4);
      float f[8] = {f0.x, f0.y, f0.z, f0.w, f1.x, f1.y, f1.z, f1.w};
      FragU kh, kl;
      #pragma unroll
      for (int c = 0; c < 4; c++) {
        unsigned int wh, wl;
        split2(f[2 * c], f[2 * c + 1], wh, wl);
        kh.u[c] = wh; kl.u[c] = wl;
      }
      accS[mt] = __builtin_amdgcn_mfma_f32_32x32x16_bf16(kh.s, qh[ks].s,  accS[mt], 0, 0, 0);
      accS[mt] = __builtin_amdgcn_mfma_f32_32x32x16_bf16(kh.s, qlo[ks].s, accS[mt], 0, 0, 0);
      accS[mt] = __builtin_amdgcn_mfma_f32_32x32x16_bf16(kl.s, qh[ks].s,  accS[mt], 0, 0, 0);
    }
  }

  // ---- softmax over the lane-local row (q = ql); partner = lane^32 ----
  float mx = -3.4e38f;
  #pragma unroll
  for (int mt = 0; mt < 4; mt++)
    #pragma unroll
    for (int r = 0; r < 16; r++) mx = fmaxf(mx, accS[mt][r]);
  mx = fmaxf(mx, __shfl_xor(mx, 32));

  float sm = 0.f;
  unsigned int w[4][8];
  #pragma unroll
  for (int mt = 0; mt < 4; mt++) {
    float p[16];
    #pragma unroll
    for (int r = 0; r < 16; r++) { p[r] = __expf(accS[mt][r] - mx); sm += p[r]; }
    #pragma unroll
    for (int c = 0; c < 8; c++) w[mt][c] = cvtpk_bf16(p[2 * c], p[2 * c + 1]);
  }
  sm += __shfl_xor(sm, 32);
  const float inv = 1.0f / sm;

  // ---- PV: y^T = mfma(A = V^T (LDS), B = P^T (in-reg)) over 8 ksteps ----
  f32x16 accY;
  #pragma unroll
  for (int r = 0; r < 16; r++) accY[r] = 0.f;
  const int vrow = ql;                      // dim = lane&31 for the A-frag
  #pragma unroll
  for (int ks = 0; ks < 8; ks++) {
    const int mt = ks >> 1, hh = ks & 1;
    // exchange packed P words with partner half (lane^32)
    unsigned int send0 = hf ? w[mt][4 * hh + 0] : w[mt][4 * hh + 2];
    unsigned int send1 = hf ? w[mt][4 * hh + 1] : w[mt][4 * hh + 3];
    unsigned int f0 = __shfl_xor(send0, 32);
    unsigned int f1 = __shfl_xor(send1, 32);
    FragU pb;
    pb.u[0] = hf ? f0 : w[mt][4 * hh + 0];
    pb.u[1] = hf ? f1 : w[mt][4 * hh + 1];
    pb.u[2] = hf ? w[mt][4 * hh + 2] : f0;
    pb.u[3] = hf ? w[mt][4 * hh + 3] : f1;
    // A-frag: Vt[dim][16ks + 8hf .. +7], swizzled chunk
    const int byte = vrow * 256 + (((2 * ks + hf) ^ (vrow & 15)) << 4);
    s16x8 vfrag = *(s16x8*)((char*)VtL + byte);
    accY = __builtin_amdgcn_mfma_f32_32x32x16_bf16(vfrag, pb.s, accY, 0, 0, 0);
  }

  // ---- store y (bf16): lane has col q = ql, rows dim = (r&3)+8*(r>>2)+4*hf
  unsigned short* orow = xb + ((size_t)(b * NN + tokQ)) * CC + hH * DD;
  #pragma unroll
  for (int rq = 0; rq < 4; rq++) {
    unsigned int u0 = cvtpk_bf16(accY[4 * rq + 0] * inv, accY[4 * rq + 1] * inv);
    unsigned int u1 = cvtpk_bf16(accY[4 * rq + 2] * inv, accY[4 * rq + 3] * inv);
    const int dim0 = 8 * rq + 4 * hf;
    *(uint2*)(orow + dim0) = make_uint2(u0, u1);
  }
}

// ---------------------------------------------------------------------------
// K5: projection out = x_bf16 @ W^T + bias via mfma_f32_16x16x32_bf16.
// Wave owns 16 m-rows x 64 n-cols; W-fragments cached in VGPRs; grid-stride
// over 4096 m-tiles. A and B frags: lane&15 = row/col, k = (lane>>4)*8 + j.
// ---------------------------------------------------------------------------
__global__ __launch_bounds__(256) void proj_kernel(
    const unsigned short* __restrict__ xb, const float* __restrict__ W,
    const float* __restrict__ bias, float* __restrict__ out)
{
  const int tid = threadIdx.x;
  const int wave = tid >> 6;
  const int lane = tid & 63;
  const int n0 = wave * 64;
  const int lr = lane & 15;       // row (A) / col (B) within tile
  const int kb = lane >> 4;       // k-block 0..3

  // cache W fragments (bf16) for this wave's 4 n-tiles x 8 k-steps
  s16x8 wf[4][8];
  #pragma unroll
  for (int nt = 0; nt < 4; nt++)
    #pragma unroll
    for (int ks = 0; ks < 8; ks++) {
      const float* wp = W + (size_t)(n0 + nt * 16 + lr) * CC + ks * 32 + kb * 8;
      float4 w0 = *(const float4*)wp;
      float4 w1 = *(const float4*)(wp + 4);
      s16x8 wv;
      wv[0] = (short)f2bf(w0.x); wv[1] = (short)f2bf(w0.y);
      wv[2] = (short)f2bf(w0.z); wv[3] = (short)f2bf(w0.w);
      wv[4] = (short)f2bf(w1.x); wv[5] = (short)f2bf(w1.y);
      wv[6] = (short)f2bf(w1.z); wv[7] = (short)f2bf(w1.w);
      wf[nt][ks] = wv;
    }
  float bs[4];
  #pragma unroll
  for (int nt = 0; nt < 4; nt++) bs[nt] = bias[n0 + nt * 16 + lr];

  const int MT = (BB * NN) / 16;  // 4096 m-tiles
  for (int mt = blockIdx.x; mt < MT; mt += gridDim.x) {
    const int m0 = mt * 16;
    const unsigned short* xrow = xb + (size_t)(m0 + lr) * CC + kb * 8;
    s16x8 a[8];
    #pragma unroll
    for (int ks = 0; ks < 8; ks++) a[ks] = *(const s16x8*)(xrow + ks * 32);
    #pragma unroll
    for (int nt = 0; nt < 4; nt++) {
      f32x4 acc = {0.f, 0.f, 0.f, 0.f};
      #pragma unroll
      for (int ks = 0; ks < 8; ks++)
        acc = __builtin_amdgcn_mfma_f32_16x16x32_bf16(a[ks], wf[nt][ks], acc, 0, 0, 0);
      const int ccol = n0 + nt * 16 + lr;
      #pragma unroll
      for (int q = 0; q < 4; q++) {
        const int row = m0 + kb * 4 + q;   // D: row=(lane>>4)*4+reg, col=lane&15
        out[(size_t)row * CC + ccol] = acc[q] + bs[nt];
      }
    }
  }
}

// ---------------------------------------------------------------------------
extern "C" void kernel_launch(void* const* d_in, const int* in_sizes, int n_in,
                              void* d_out, int out_size, void* d_ws, size_t ws_size,
                              hipStream_t stream)
{
  (void)in_sizes; (void)n_in; (void)out_size; (void)ws_size;
  const float* qkv  = (const float*)d_in[0];
  const float* sim  = (const float*)d_in[1];
  const float* W    = (const float*)d_in[2];
  const float* bias = (const float*)d_in[3];
  const float* lsp  = (const float*)d_in[4];
  float* out = (float*)d_out;

  // workspace layout (~34.1 MB)
  char* ws = (char*)d_ws;
  unsigned short* xb = (unsigned short*)ws;                 // [B*N][C] bf16, 32 MB
  size_t off = (size_t)BB * NN * CC * sizeof(unsigned short);
  int* srcOf = (int*)(ws + off); off += (size_t)BB * NN * sizeof(int);
  int* cat   = (int*)(ws + off); off += (size_t)BB * NN * sizeof(int);
  int* hist  = (int*)(ws + off); off += (size_t)BB * TT * sizeof(int);
  int* catStart = (int*)(ws + off);

  (void)hipMemsetAsync(hist, 0, BB * TT * sizeof(int), stream);
  cat_hist_kernel<<<(BB * NN) / 256, 256, 0, stream>>>(sim, cat, hist);
  prefix_kernel<<<1, 64, 0, stream>>>(hist, catStart);
  sort_positions_kernel<<<BB * TT, 256, 0, stream>>>(cat, catStart, srcOf);
  attn_kernel<<<BB * NGR * HH, 256, 0, stream>>>(qkv, srcOf, lsp, xb);
  proj_kernel<<<512, 256, 0, stream>>>(xb, W, bias, out);
}